// Round 1
// baseline (792.157 us; speedup 1.0000x reference)
//
#include <hip/hip_runtime.h>
#include <math.h>

#define P_DIM 4096
#define D_DIM 1024
#define NREF 256
#define NEXTRA 16384      // 4 * P_DIM
#define BM 64
#define BN 64
#define BK 32
#define PAD 4
#define NCHUNK (NEXTRA / BN)   // 256
#define NEG_INF (-3.4e38f)

// Total KL rows: d1 = 3*2*256 = 1536 ; d2 = 2*256*4 = 2048 ; d3 = 3*2*256*4 = 6144
#define KL_ROWS 9728

__device__ __forceinline__ float wave_reduce_sum(float v) {
  #pragma unroll
  for (int off = 32; off >= 1; off >>= 1) v += __shfl_xor(v, off, 64);
  return v;
}
__device__ __forceinline__ float wave_reduce_max(float v) {
  #pragma unroll
  for (int off = 32; off >= 1; off >>= 1) v = fmaxf(v, __shfl_xor(v, off, 64));
  return v;
}

__global__ void zero_acc_kernel(float* __restrict__ acc) {
  if (threadIdx.x < 4) acc[threadIdx.x] = 0.0f;
}

// inv_norm[b*NEXTRA + e] = 1 / max(||extra_t[b, e, :]||, 1e-12)
__global__ __launch_bounds__(256) void extra_norm_kernel(
    const float* __restrict__ teacher, float* __restrict__ inv_norm) {
  const int w = (int)((blockIdx.x * 256 + threadIdx.x) >> 6);
  const int lane = threadIdx.x & 63;
  const int b = w >> 14;
  const int e = w & (NEXTRA - 1);
  const float* row = teacher +
      ((size_t)(b * 8 + 1 + 2 * (e >> 12)) * P_DIM + (e & (P_DIM - 1))) * D_DIM;
  float s = 0.0f;
  #pragma unroll
  for (int j = 0; j < 4; ++j) {
    float4 v = *(const float4*)(row + 4 * (lane + 64 * j));
    s += v.x * v.x + v.y * v.y + v.z * v.z + v.w * v.w;
  }
  s = wave_reduce_sum(s);
  if (lane == 0) inv_norm[w] = 1.0f / fmaxf(sqrtf(s), 1e-12f);
}

// Per-block: 64x64 tile of score(r,e) = dot(ref_raw[r], extra_raw[e]) * inv_norm[e]
// (ref normalization dropped: positive per-row scale doesn't change top-k order).
// Emits per-row top-4 candidates for this 64-column chunk.
__global__ __launch_bounds__(256) void gemm_topk_kernel(
    const float* __restrict__ teacher, const int* __restrict__ ref_perm,
    const float* __restrict__ inv_norm,
    float* __restrict__ cand_val, int* __restrict__ cand_idx) {
  __shared__ float As[BK][BM + PAD];
  __shared__ float Bs[BK][BN + PAD];
  __shared__ float Ss[BM][BN + 1];

  const int nblk = blockIdx.x;   // N chunk
  const int mblk = blockIdx.y;   // M chunk
  const int b    = blockIdx.z;
  const int tid  = threadIdx.x;
  const int tx = tid & 15;       // output col group
  const int ty = tid >> 4;       // output row group

  // staging: each thread loads 2 float4 (rows row0,row1; float cols c4..c4+3)
  const int row0 = tid >> 3;          // 0..31
  const int c4   = (tid & 7) * 4;     // 0,4,..,28
  const int row1 = row0 + 32;

  const size_t batch_off = (size_t)b * 8 * P_DIM * D_DIM;
  const float* Aptr0 = teacher + batch_off +
      (size_t)ref_perm[mblk * BM + row0] * D_DIM + c4;
  const float* Aptr1 = teacher + batch_off +
      (size_t)ref_perm[mblk * BM + row1] * D_DIM + c4;
  const int e0 = nblk * BN;
  const int eA = e0 + row0, eB = e0 + row1;
  const float* Bptr0 = teacher + batch_off +
      ((size_t)(1 + 2 * (eA >> 12)) * P_DIM + (eA & (P_DIM - 1))) * D_DIM + c4;
  const float* Bptr1 = teacher + batch_off +
      ((size_t)(1 + 2 * (eB >> 12)) * P_DIM + (eB & (P_DIM - 1))) * D_DIM + c4;

  float acc[4][4] = {};

  for (int kk = 0; kk < D_DIM; kk += BK) {
    const float4 a0 = *(const float4*)(Aptr0 + kk);
    const float4 a1 = *(const float4*)(Aptr1 + kk);
    const float4 b0 = *(const float4*)(Bptr0 + kk);
    const float4 b1 = *(const float4*)(Bptr1 + kk);
    __syncthreads();  // previous iteration's reads done
    As[c4 + 0][row0] = a0.x; As[c4 + 1][row0] = a0.y;
    As[c4 + 2][row0] = a0.z; As[c4 + 3][row0] = a0.w;
    As[c4 + 0][row1] = a1.x; As[c4 + 1][row1] = a1.y;
    As[c4 + 2][row1] = a1.z; As[c4 + 3][row1] = a1.w;
    Bs[c4 + 0][row0] = b0.x; Bs[c4 + 1][row0] = b0.y;
    Bs[c4 + 2][row0] = b0.z; Bs[c4 + 3][row0] = b0.w;
    Bs[c4 + 0][row1] = b1.x; Bs[c4 + 1][row1] = b1.y;
    Bs[c4 + 2][row1] = b1.z; Bs[c4 + 3][row1] = b1.w;
    __syncthreads();
    #pragma unroll 8
    for (int k = 0; k < BK; ++k) {
      float av[4], bv[4];
      #pragma unroll
      for (int i = 0; i < 4; ++i) av[i] = As[k][ty * 4 + i];
      #pragma unroll
      for (int j = 0; j < 4; ++j) bv[j] = Bs[k][tx + 16 * j];
      #pragma unroll
      for (int i = 0; i < 4; ++i)
        #pragma unroll
        for (int j = 0; j < 4; ++j) acc[i][j] += av[i] * bv[j];
    }
  }

  // scale by extra inv-norm, stash tile in LDS
  const int ebase = b * NEXTRA + e0;
  #pragma unroll
  for (int i = 0; i < 4; ++i)
    #pragma unroll
    for (int j = 0; j < 4; ++j)
      Ss[ty * 4 + i][tx + 16 * j] = acc[i][j] * inv_norm[ebase + tx + 16 * j];
  __syncthreads();

  // per-row top-4 within this 64-col chunk (strict '>' keeps lowest index on ties)
  if (tid < BM) {
    const float* srow = Ss[tid];
    float bv0 = NEG_INF, bv1 = NEG_INF, bv2 = NEG_INF, bv3 = NEG_INF;
    int bi0 = 0, bi1 = 0, bi2 = 0, bi3 = 0;
    for (int c = 0; c < BN; ++c) {
      const float v = srow[c];
      const int gi = e0 + c;
      if (v > bv3) {
        if (v > bv0) { bv3=bv2; bi3=bi2; bv2=bv1; bi2=bi1; bv1=bv0; bi1=bi0; bv0=v; bi0=gi; }
        else if (v > bv1) { bv3=bv2; bi3=bi2; bv2=bv1; bi2=bi1; bv1=v; bi1=gi; }
        else if (v > bv2) { bv3=bv2; bi3=bi2; bv2=v; bi2=gi; }
        else { bv3=v; bi3=gi; }
      }
    }
    const size_t base = (((size_t)b * NREF + mblk * BM + tid) * NCHUNK + nblk) * 4;
    cand_val[base + 0] = bv0; cand_idx[base + 0] = bi0;
    cand_val[base + 1] = bv1; cand_idx[base + 1] = bi1;
    cand_val[base + 2] = bv2; cand_idx[base + 2] = bi2;
    cand_val[base + 3] = bv3; cand_idx[base + 3] = bi3;
  }
}

// one wave per (b, r): merge 256 chunks x 4 candidates -> global top-4 indices
__global__ void topk_merge_kernel(const float* __restrict__ cand_val,
                                  const int* __restrict__ cand_idx,
                                  int* __restrict__ topk_idx) {
  const int br = blockIdx.x;     // b*NREF + r
  const int lane = threadIdx.x;  // 0..63
  float v[16]; int id[16];
  const size_t base = (size_t)br * (NCHUNK * 4);
  #pragma unroll
  for (int j = 0; j < 16; ++j) {
    const int c = lane + 64 * j;
    v[j] = cand_val[base + c];
    id[j] = cand_idx[base + c];
  }
  #pragma unroll
  for (int t = 0; t < 4; ++t) {
    float bv = NEG_INF; int bi = 0x7fffffff;
    #pragma unroll
    for (int j = 0; j < 16; ++j)
      if (v[j] > bv || (v[j] == bv && id[j] < bi)) { bv = v[j]; bi = id[j]; }
    #pragma unroll
    for (int off = 32; off >= 1; off >>= 1) {
      const float ov = __shfl_xor(bv, off, 64);
      const int   oi = __shfl_xor(bi, off, 64);
      if (ov > bv || (ov == bv && oi < bi)) { bv = ov; bi = oi; }
    }
    if (lane == 0) topk_idx[br * 4 + t] = bi;
    #pragma unroll
    for (int j = 0; j < 16; ++j)
      if (id[j] == bi) v[j] = NEG_INF;   // indices are globally unique
  }
}

// One wave per KL row. KL = sum p*(dt-ds) - (Mt + log St) + (Ms + log Ss),
// then smooth-L1(beta=0.5) accumulated per-distance.
__global__ __launch_bounds__(256) void kl_kernel(
    const float* __restrict__ teacher, const float* __restrict__ student,
    const int* __restrict__ ref_perm, const int* __restrict__ shared_perm,
    const int* __restrict__ topk_idx, float* __restrict__ acc) {
  const int w = (int)((blockIdx.x * 256 + threadIdx.x) >> 6);
  const int lane = threadIdx.x & 63;
  if (w >= KL_ROWS) return;

  const float *pt, *qt, *ps, *qs;
  int accIdx;
  if (w < 1536) {                      // d1: pair p, batch b, ref row r
    const int p = w / 512, rem = w - p * 512, b = rem >> 8, r = rem & 255;
    const int rp = ref_perm[r], sp = shared_perm[r];
    pt = teacher + ((size_t)(b * 8) * P_DIM + rp) * D_DIM;
    qt = teacher + ((size_t)(b * 8 + 2 * p + 2) * P_DIM + sp) * D_DIM;  // SHARED_TEACHER = 2p+2
    ps = student + ((size_t)(b * 4) * P_DIM + rp) * D_DIM;
    qs = student + ((size_t)(b * 4 + p + 1) * P_DIM + sp) * D_DIM;      // SHARED_STUDENT = p+1
    accIdx = 0;
  } else if (w < 3584) {               // d2 (pair-independent, computed once)
    const int w2 = w - 1536, b = w2 >> 10, rem = w2 & 1023, r = rem >> 2, k = rem & 3;
    const int rp = ref_perm[r];
    const int e = topk_idx[(b * NREF + r) * 4 + k];
    pt = teacher + ((size_t)(b * 8) * P_DIM + rp) * D_DIM;
    qt = teacher + ((size_t)(b * 8 + 1 + 2 * (e >> 12)) * P_DIM + (e & (P_DIM - 1))) * D_DIM;
    ps = student + ((size_t)(b * 4) * P_DIM + rp) * D_DIM;
    qs = qt;
    accIdx = 1;
  } else {                             // d3
    const int w3 = w - 3584, p = w3 >> 11;
    const int rem = w3 & 2047, b = rem >> 10, rem2 = rem & 1023, r = rem2 >> 2, k = rem2 & 3;
    const int sp = shared_perm[r];
    const int e = topk_idx[(b * NREF + r) * 4 + k];
    pt = teacher + ((size_t)(b * 8 + 2 * p + 2) * P_DIM + sp) * D_DIM;
    qt = teacher + ((size_t)(b * 8 + 1 + 2 * (e >> 12)) * P_DIM + (e & (P_DIM - 1))) * D_DIM;
    ps = student + ((size_t)(b * 4 + p + 1) * P_DIM + sp) * D_DIM;
    qs = qt;
    accIdx = 2;
  }

  float dt[16], dss[16];
  #pragma unroll
  for (int j = 0; j < 4; ++j) {
    const int off = 4 * (lane + 64 * j);
    const float4 a  = *(const float4*)(pt + off);
    const float4 c  = *(const float4*)(qt + off);
    const float4 d  = *(const float4*)(ps + off);
    const float4 e4 = *(const float4*)(qs + off);
    dt [4*j+0] = a.x - c.x;  dt [4*j+1] = a.y - c.y;
    dt [4*j+2] = a.z - c.z;  dt [4*j+3] = a.w - c.w;
    dss[4*j+0] = d.x - e4.x; dss[4*j+1] = d.y - e4.y;
    dss[4*j+2] = d.z - e4.z; dss[4*j+3] = d.w - e4.w;
  }
  float mt = NEG_INF, ms = NEG_INF;
  #pragma unroll
  for (int i = 0; i < 16; ++i) { mt = fmaxf(mt, dt[i]); ms = fmaxf(ms, dss[i]); }
  mt = wave_reduce_max(mt);
  ms = wave_reduce_max(ms);
  float st = 0.0f, ssum = 0.0f, wt = 0.0f;
  #pragma unroll
  for (int i = 0; i < 16; ++i) {
    const float et = expf(dt[i] - mt);
    st += et;
    wt += et * (dt[i] - dss[i]);
    ssum += expf(dss[i] - ms);
  }
  st = wave_reduce_sum(st);
  ssum = wave_reduce_sum(ssum);
  wt = wave_reduce_sum(wt);
  if (lane == 0) {
    const float kl = wt / st - (mt + logf(st)) + (ms + logf(ssum));
    const float ax = fabsf(kl);
    const float sl = ax < 0.5f ? kl * kl : ax - 0.25f;
    atomicAdd(&acc[accIdx], sl);
  }
}

__global__ void finalize_kernel(const float* __restrict__ acc, float* __restrict__ out) {
  if (threadIdx.x == 0)
    out[0] = acc[0] * (1.0f / 1536.0f) + acc[1] * (1.0f / 2048.0f) +
             acc[2] * (1.0f / 6144.0f);
}

extern "C" void kernel_launch(void* const* d_in, const int* in_sizes, int n_in,
                              void* d_out, int out_size, void* d_ws, size_t ws_size,
                              hipStream_t stream) {
  const float* teacher     = (const float*)d_in[0];
  const float* student     = (const float*)d_in[1];
  const int*   ref_perm    = (const int*)d_in[2];
  const int*   shared_perm = (const int*)d_in[3];
  float* out = (float*)d_out;

  float* ws = (float*)d_ws;
  float* acc      = ws;                      // 4 floats
  float* inv_norm = ws + 256;                // 2*16384 floats
  float* cand_val = ws + 256 + 2 * NEXTRA;   // 2*256*256*4 = 2097152 floats
  int*   cand_idx = (int*)(cand_val + 2097152);
  int*   topk_idx = (int*)(cand_idx + 2097152);  // 2*256*4 ints

  zero_acc_kernel<<<1, 64, 0, stream>>>(acc);
  extra_norm_kernel<<<(2 * NEXTRA) / 4, 256, 0, stream>>>(teacher, inv_norm);
  dim3 gg(NCHUNK, NREF / BM, 2);
  gemm_topk_kernel<<<gg, 256, 0, stream>>>(teacher, ref_perm, inv_norm,
                                           cand_val, cand_idx);
  topk_merge_kernel<<<2 * NREF, 64, 0, stream>>>(cand_val, cand_idx, topk_idx);
  kl_kernel<<<KL_ROWS / 4, 256, 0, stream>>>(teacher, student, ref_perm,
                                             shared_perm, topk_idx, acc);
  finalize_kernel<<<1, 64, 0, stream>>>(acc, out);
}